// Round 1
// 991.807 us; speedup vs baseline: 1.0708x; 1.0708x over previous
//
#include <hip/hip_runtime.h>

// Euclidean cdist: out[b,j] = ||x[b,:] - w[:,j]||, B=4096 D=64 K=50000, fp32.
// v2: swapped-operand MFMA (D = W·X, transposed) so each lane's 4 acc regs are
// 4 CONSECUTIVE K-columns of one output row -> global_store_dwordx4 (16 vector
// stores/thread vs 64 scalar). x fragments built directly from global (x is
// L2-resident; no LDS round trip, no separate norm pass — row norms via
// __shfl_xor). w col-norms fused into the staging loop (partials in LDS,
// summed in epilogue) -> single barrier per block. Raw v_sqrt_f32, NT stores.

typedef __bf16 bf16x8 __attribute__((ext_vector_type(8)));
typedef float floatx4 __attribute__((ext_vector_type(4)));
typedef float float4v __attribute__((ext_vector_type(4)));

constexpr int Bb = 4096;
constexpr int Dd = 64;
constexpr int Kk = 50000;
constexpr int BM = 128;
constexpr int BN = 128;
constexpr int LDA = 72;  // bf16 elems per LDS row (64 + 8 pad -> 2-way bank alias = free)

__device__ __forceinline__ unsigned short f2bf(float f) {
  union { float f; unsigned u; } v; v.f = f;
  unsigned r = v.u + 0x7FFFu + ((v.u >> 16) & 1u);  // round-to-nearest-even
  return (unsigned short)(r >> 16);
}
__device__ __forceinline__ float bf2f(unsigned short h) {
  union { unsigned u; float f; } v; v.u = ((unsigned)h) << 16;
  return v.f;
}

__global__ __launch_bounds__(256, 4) void euclid_kernel(
    const float* __restrict__ x, const float* __restrict__ w,
    float* __restrict__ out) {
  __shared__ alignas(16) unsigned short Bs[BN * LDA];  // w^T tile [col][k] bf16
  __shared__ alignas(16) float w2p[2][BN];             // col-norm partials

  const int tid = threadIdx.x;
  const int m0 = blockIdx.x * BM;   // x-fastest: 32 consecutive blocks share w-tile in L2
  const int j0 = blockIdx.y * BN;

  const int wv = tid >> 6;
  const int lane = tid & 63;
  const int l15 = lane & 15;
  const int quad = lane >> 4;

  // ---- x fragments straight from global (bf16-rounded) + per-lane row norms ----
  // MFMA B-operand layout: col = l15 (x row), k = kc*32 + quad*8 + j.
  bf16x8 a[2][2];   // a[ri][kc]
  float x2r[2];
#pragma unroll
  for (int ri = 0; ri < 2; ++ri) {
    const int grow = m0 + 32 * wv + 16 * ri + l15;
    const float4v* xp = (const float4v*)(x + (size_t)grow * Dd);
    float s = 0.f;
#pragma unroll
    for (int kc = 0; kc < 2; ++kc) {
      float4v v0 = xp[kc * 8 + quad * 2];
      float4v v1 = xp[kc * 8 + quad * 2 + 1];
      union { bf16x8 v; unsigned short us[8]; } u;
      u.us[0] = f2bf(v0.x); u.us[1] = f2bf(v0.y);
      u.us[2] = f2bf(v0.z); u.us[3] = f2bf(v0.w);
      u.us[4] = f2bf(v1.x); u.us[5] = f2bf(v1.y);
      u.us[6] = f2bf(v1.z); u.us[7] = f2bf(v1.w);
#pragma unroll
      for (int j = 0; j < 8; ++j) {
        float rv = bf2f(u.us[j]);
        s = fmaf(rv, rv, s);
      }
      a[ri][kc] = u.v;
    }
    // lanes {l15, l15+16, l15+32, l15+48} hold partials of the same row
    s += __shfl_xor(s, 16);
    s += __shfl_xor(s, 32);
    x2r[ri] = s;
  }

  // ---- stage w tile -> bf16 LDS (transposed) with fused col-norm partials ----
  {
    const int c = tid & 127;
    const int g = tid >> 7;       // k-parity group: {0,1}+4t vs {2,3}+4t
    const int gc = j0 + c;
    const bool valid = gc < Kk;
    const float* wp = w + gc;
    float s = 0.f;
#pragma unroll
    for (int k = 2 * g; k < Dd; k += 4) {
      float v0 = valid ? wp[(size_t)k * Kk] : 0.0f;
      float v1 = valid ? wp[(size_t)(k + 1) * Kk] : 0.0f;
      unsigned short h0 = f2bf(v0), h1 = f2bf(v1);
      float r0 = bf2f(h0), r1 = bf2f(h1);
      s = fmaf(r0, r0, s);
      s = fmaf(r1, r1, s);
      *(unsigned*)&Bs[c * LDA + k] = (unsigned)h0 | ((unsigned)h1 << 16);
    }
    w2p[g][c] = s;
  }
  __syncthreads();   // the only barrier: Bs + w2p ready

  // ---- MFMA, swapped operands: D[m=wcol][n=xrow] = sum_k w[m][k]*x[n][k] ----
  floatx4 acc[2][8];
#pragma unroll
  for (int ri = 0; ri < 2; ++ri)
#pragma unroll
    for (int ci = 0; ci < 8; ++ci)
      acc[ri][ci] = (floatx4){0.f, 0.f, 0.f, 0.f};

#pragma unroll
  for (int ci = 0; ci < 8; ++ci) {
    bf16x8 b0 = *(const bf16x8*)&Bs[(16 * ci + l15) * LDA + quad * 8];
    bf16x8 b1 = *(const bf16x8*)&Bs[(16 * ci + l15) * LDA + 32 + quad * 8];
#pragma unroll
    for (int ri = 0; ri < 2; ++ri) {
      acc[ri][ci] = __builtin_amdgcn_mfma_f32_16x16x32_bf16(b0, a[ri][0], acc[ri][ci], 0, 0, 0);
      acc[ri][ci] = __builtin_amdgcn_mfma_f32_16x16x32_bf16(b1, a[ri][1], acc[ri][ci], 0, 0, 0);
    }
  }

  // ---- epilogue: lane holds rows (ri,l15) x cols quad*4+{0..3} per ci ----
  // C/D layout: "col"=l15 -> x row, "row"=quad*4+reg -> w col (K axis).
#pragma unroll
  for (int ri = 0; ri < 2; ++ri) {
    const int grow = m0 + 32 * wv + 16 * ri + l15;
    float* po = out + (size_t)grow * Kk + j0 + quad * 4;
    const float xx = x2r[ri];
#pragma unroll
    for (int ci = 0; ci < 8; ++ci) {
      const int gcol = j0 + 16 * ci + quad * 4;
      if (gcol >= Kk) continue;   // K%16==0 -> float4 fully valid or fully out
      float4v wq0 = *(const float4v*)&w2p[0][16 * ci + quad * 4];
      float4v wq1 = *(const float4v*)&w2p[1][16 * ci + quad * 4];
      float4v o;
#pragma unroll
      for (int r = 0; r < 4; ++r) {
        float t = xx + (wq0[r] + wq1[r]);
        float sq = fmaf(-2.0f, acc[ri][ci][r], t);
        sq = fmaxf(sq, 1e-12f);
        o[r] = __builtin_amdgcn_sqrtf(sq);
      }
      __builtin_nontemporal_store(o, (float4v*)(po + 16 * ci));
    }
  }
}

extern "C" void kernel_launch(void* const* d_in, const int* in_sizes, int n_in,
                              void* d_out, int out_size, void* d_ws, size_t ws_size,
                              hipStream_t stream) {
  const float* x = (const float*)d_in[0];
  const float* w = (const float*)d_in[1];
  float* out = (float*)d_out;
  dim3 grid(Bb / BM, (Kk + BN - 1) / BN);  // (32, 391)
  euclid_kernel<<<grid, dim3(256), 0, stream>>>(x, w, out);
}